// Round 3
// baseline (476.898 us; speedup 1.0000x reference)
//
#include <hip/hip_runtime.h>

// LinearAttention: B=4, S=4096, D=1024, H=16, DK=64
// R6 == R5 resubmit (R5 bench was an infra failure: container acquisition
// flake, no kernel error). Design:
//  (a) cast3 ELIMINATED -- proj reads fp32 A directly, reg-stages (T14:
//      issue loads early / cvt+swizzled ds_write at K-tile boundary);
//  (b) proj z-loop: one 256-block dispatch, flat 48-K-tile pipeline over
//      q/k/v (one prologue, no 3-wave tail);
//  (c) cast4+memset fused into one prep kernel. 7 -> 5 dispatches.
// R4 result: 8-phase+swizzle proj = 793 TF, bank-conflict 0, at the ~850 TF
//      structural ceiling for 256^2/8ph at K=1024 (m248).

typedef unsigned short ushort_t;
typedef __bf16 bf16x8 __attribute__((ext_vector_type(8)));
typedef float f32x4 __attribute__((ext_vector_type(4)));
typedef void gvoid_t __attribute__((address_space(1)));
typedef void svoid_t __attribute__((address_space(3)));

#define BB 4
#define SS 4096
#define DD 1024
#define HH 16
#define DKk 64
#define MM (BB * SS) /* 16384 */
#define NKT 16       /* K=1024 in 16 tiles of 64 */
#define NG 48        /* 3 GEMMs x 16 K-tiles, flat pipeline */

__device__ __forceinline__ ushort_t f2bf(float f) {
  unsigned int u = __float_as_uint(f);
  u += 0x7fffu + ((u >> 16) & 1u); // RNE
  return (ushort_t)(u >> 16);
}
__device__ __forceinline__ float b2f(ushort_t h) {
  return __uint_as_float(((unsigned int)h) << 16);
}
__device__ __forceinline__ void gld_lds16(const ushort_t* g, ushort_t* l) {
  // async global->LDS, 16B per lane; LDS dest = wave-uniform base + lane*16
  __builtin_amdgcn_global_load_lds((gvoid_t*)g, (svoid_t*)l, 16, 0, 0);
}
__device__ __forceinline__ bf16x8 ldfrag(const ushort_t* p) {
  return *(const bf16x8*)p; // 16B aligned at all call sites
}
#define MEMFENCE asm volatile("" ::: "memory")

// ---------------- prep: cast 4 weight mats fp32->bf16 + zero KVt/Ksum ------
__global__ __launch_bounds__(256) void prep_kernel(
    const float* __restrict__ a, const float* __restrict__ b,
    const float* __restrict__ c, const float* __restrict__ e,
    ushort_t* __restrict__ ad, ushort_t* __restrict__ bd,
    ushort_t* __restrict__ cd, ushort_t* __restrict__ ed,
    float* __restrict__ zbuf) {
  const int z = blockIdx.y;
  if (z == 4) { // zero KVt (64*4096) + Ksum (64*64)
    const size_t tot = (size_t)64 * 4096 + 64 * 64;
    for (size_t j = (size_t)blockIdx.x * 256 + threadIdx.x; j < tot; j += (size_t)1024 * 256)
      zbuf[j] = 0.f;
    return;
  }
  const float* s = (z == 0) ? a : (z == 1) ? b : (z == 2) ? c : e;
  ushort_t* d = (z == 0) ? ad : (z == 1) ? bd : (z == 2) ? cd : ed;
  size_t i = ((size_t)blockIdx.x * 256 + threadIdx.x) * 4;
  float4 f = *(const float4*)(s + i);
  ushort4 o;
  o.x = f2bf(f.x); o.y = f2bf(f.y); o.z = f2bf(f.z); o.w = f2bf(f.w);
  *(ushort4*)(d + i) = o;
}

// ================= fused projection GEMM (fp32 A, z-loop) =================
// Y(z) = act(A_z[16384,1024] * W_z[1024,1024]^T), z in {q,k,v}.
// BM=BN=256, BK=64, 512 thr = 8 waves (2x4), per-wave 128x64, acc[8][4].
// 8-phase schedule, counted vmcnt; A reg-staged from fp32 (cvt at boundary,
// XOR-swizzled ds_write); B bf16 via global_load_lds w/ pre-swizzled source.
// vmcnt ledger (plain loads + gld_lds share the in-order counter):
//   entering gk: outstanding = B(gk+1)x4
//   gk issues: A(gk+1)x8 (ph0,ph1) + B(gk+2)x4 (ph2,ph3)
//   boundary vmcnt(4): retires B(gk+1)+A(gk+1); B(gk+2) stays in flight.
__global__ __launch_bounds__(512, 2) void projf_kernel(
    const float* __restrict__ qf, const float* __restrict__ kf, const float* __restrict__ vf,
    const ushort_t* __restrict__ wq, const ushort_t* __restrict__ wk, const ushort_t* __restrict__ wv,
    ushort_t* __restrict__ Qp, ushort_t* __restrict__ Kp, ushort_t* __restrict__ Vp) {
  __shared__ __align__(16) ushort_t As[2][2][8192];
  __shared__ __align__(16) ushort_t Bs[2][2][8192];
  const int raw = blockIdx.x;                       // 256 = 8 XCD * 32
  const int logical = (raw & 7) * 32 + (raw >> 3);  // bijective chunked XCD swizzle
  const int m0 = (logical >> 2) * 256, n0 = (logical & 3) * 256;
  const int t = threadIdx.x;
  const int w = t >> 6, lane = t & 63, q4 = lane >> 4, l16 = lane & 15;
  const int wr = w >> 2, wc = w & 3;                // 2(M) x 4(N) waves; tile 128x64
  const int srow = t >> 3, scol = ((t & 7) ^ (srow & 7)) * 8; // B staging (pre-swz src)
  const int arow = t >> 2, acol = (t & 3) * 16;     // A staging: row 0..127, 16 floats
  const int ag0 = (t & 3) * 2;                      // A granule pair base (granule=8bf16)
  const int swz = l16 & 7;

  auto Asel = [&](int z) { return z == 0 ? qf : (z == 1 ? kf : vf); };
  auto Wsel = [&](int z) { return z == 0 ? wq : (z == 1 ? wk : wv); };
  auto Ysel = [&](int z) { return z == 0 ? Qp : (z == 1 ? Kp : Vp); };

  f32x4 acc[8][4];
  const f32x4 zero = {0.f, 0.f, 0.f, 0.f};
#pragma unroll
  for (int i = 0; i < 8; ++i)
#pragma unroll
    for (int j = 0; j < 4; ++j) acc[i][j] = zero;

  auto rdA = [&](int c, int mi, int kk) -> bf16x8 {
    const int rowh = mi * 16 + l16;
    const int slot = (kk * 4 + q4) ^ swz;
    return ldfrag(&As[c][wr][rowh * 64 + slot * 8]);
  };
  auto rdB = [&](int c, int ni, int kk) -> bf16x8 {
    const int rowh = (wc & 1) * 64 + ni * 16 + l16;
    const int slot = (kk * 4 + q4) ^ swz;
    return ldfrag(&Bs[c][wc >> 1][rowh * 64 + slot * 8]);
  };
  auto stageB = [&](const ushort_t* Wz, int c, int h, int kt) {
    const ushort_t* g = Wz + (size_t)(n0 + h * 128 + srow) * 1024 + kt * 64 + scol;
    gld_lds16(g, &Bs[c][h][t * 8]);
    gld_lds16(g + 64 * 1024, &Bs[c][h][4096 + t * 8]);
  };

  float4 areg[2][4]; // fp32 A staged in regs: [half][4x float4]
  auto loadA = [&](const float* Az, int h, int kt) {
    const float* g = Az + (size_t)(m0 + h * 128 + arow) * 1024 + kt * 64 + acol;
    areg[h][0] = ((const float4*)g)[0];
    areg[h][1] = ((const float4*)g)[1];
    areg[h][2] = ((const float4*)g)[2];
    areg[h][3] = ((const float4*)g)[3];
  };
  auto writeA = [&](int c) { // cvt + XOR-swizzled ds_write (matches rdA XOR)
#pragma unroll
    for (int h = 0; h < 2; ++h) {
      bf16x8 p0, p1;
#pragma unroll
      for (int j = 0; j < 4; ++j) {
        p0[j] = (__bf16)areg[h][0][j]; p0[j + 4] = (__bf16)areg[h][1][j];
        p1[j] = (__bf16)areg[h][2][j]; p1[j + 4] = (__bf16)areg[h][3][j];
      }
      *(bf16x8*)&As[c][h][arow * 64 + ((ag0)     ^ (arow & 7)) * 8] = p0;
      *(bf16x8*)&As[c][h][arow * 64 + ((ag0 + 1) ^ (arow & 7)) * 8] = p1;
    }
  };
  auto epilogue = [&](int z) {
    ushort_t* Y = Ysel(z);
    const bool act = (z < 2);
#pragma unroll
    for (int mi = 0; mi < 8; ++mi)
#pragma unroll
      for (int ni = 0; ni < 4; ++ni) {
        const int col = n0 + wc * 64 + ni * 16 + l16;
#pragma unroll
        for (int r = 0; r < 4; ++r) {
          const int row = m0 + wr * 128 + mi * 16 + q4 * 4 + r;
          float vv = acc[mi][ni][r];
          if (act) vv = (vv > 0.f) ? (vv + 1.f) : __expf(vv); // elu(x)+1
          Y[(size_t)row * 1024 + col] = f2bf(vv);
          acc[mi][ni][r] = 0.f;
        }
      }
  };

  // ---- prologue: A(0) regs; B(0)->buf0, B(1)->buf1. Issue order pinned. ----
  loadA(Asel(0), 0, 0); loadA(Asel(0), 1, 0);          // 8 loads
  MEMFENCE;
  stageB(Wsel(0), 0, 0, 0); stageB(Wsel(0), 0, 1, 0);  // 4 gld_lds (kt0)
  MEMFENCE;
  stageB(Wsel(0), 1, 0, 1); stageB(Wsel(0), 1, 1, 1);  // 4 gld_lds (kt1)
  asm volatile("s_waitcnt vmcnt(4)" ::: "memory");     // A(0)+B(0) done; B(1) flies
  writeA(0);
  asm volatile("s_waitcnt lgkmcnt(0)" ::: "memory");
  __builtin_amdgcn_s_barrier();

  // steady-state invariant entering gk: outstanding = B(gk+1) x4
  bf16x8 aR[4][2], b0[2][2], b1[2][2];
#pragma unroll 2
  for (int gk = 0; gk < NG; ++gk) {
    const int c = gk & 1;
    const int kt = gk & 15;
    // ---- phase 0: quad (mi0-3 x ni0-1); issue A0-half loads of gk+1 ----
#pragma unroll
    for (int mi = 0; mi < 4; ++mi) { aR[mi][0] = rdA(c, mi, 0); aR[mi][1] = rdA(c, mi, 1); }
#pragma unroll
    for (int ni = 0; ni < 2; ++ni) { b0[ni][0] = rdB(c, ni, 0); b0[ni][1] = rdB(c, ni, 1); }
    if (gk + 1 < NG) loadA(Asel((gk + 1) >> 4), 0, (gk + 1) & 15);
    __builtin_amdgcn_s_barrier();
    asm volatile("s_waitcnt lgkmcnt(0)" ::: "memory");
    __builtin_amdgcn_sched_barrier(0);
    __builtin_amdgcn_s_setprio(1);
#pragma unroll
    for (int mi = 0; mi < 4; ++mi)
#pragma unroll
      for (int ni = 0; ni < 2; ++ni) {
        acc[mi][ni] = __builtin_amdgcn_mfma_f32_16x16x32_bf16(aR[mi][0], b0[ni][0], acc[mi][ni], 0, 0, 0);
        acc[mi][ni] = __builtin_amdgcn_mfma_f32_16x16x32_bf16(aR[mi][1], b0[ni][1], acc[mi][ni], 0, 0, 0);
      }
    __builtin_amdgcn_s_setprio(0);
    __builtin_amdgcn_s_barrier();
    // ---- phase 1: quad (mi0-3 x ni2-3); issue A1-half loads of gk+1 ----
#pragma unroll
    for (int ni = 0; ni < 2; ++ni) { b1[ni][0] = rdB(c, ni + 2, 0); b1[ni][1] = rdB(c, ni + 2, 1); }
    if (gk + 1 < NG) loadA(Asel((gk + 1) >> 4), 1, (gk + 1) & 15);
    __builtin_amdgcn_s_barrier();
    asm volatile("s_waitcnt lgkmcnt(0)" ::: "memory");
    __builtin_amdgcn_sched_barrier(0);
    __builtin_amdgcn_s_setprio(1);
#pragma unroll
    for (int mi = 0; mi < 4; ++mi)
#pragma unroll
      for (int ni = 0; ni < 2; ++ni) {
        acc[mi][ni + 2] = __builtin_amdgcn_mfma_f32_16x16x32_bf16(aR[mi][0], b1[ni][0], acc[mi][ni + 2], 0, 0, 0);
        acc[mi][ni + 2] = __builtin_amdgcn_mfma_f32_16x16x32_bf16(aR[mi][1], b1[ni][1], acc[mi][ni + 2], 0, 0, 0);
      }
    __builtin_amdgcn_s_setprio(0);
    __builtin_amdgcn_s_barrier();
    // ---- phase 2: quad (mi4-7 x ni0-1); issue B0-half gld_lds of gk+2 ----
#pragma unroll
    for (int mi = 0; mi < 4; ++mi) { aR[mi][0] = rdA(c, mi + 4, 0); aR[mi][1] = rdA(c, mi + 4, 1); }
    if (gk + 2 < NG) stageB(Wsel((gk + 2) >> 4), c, 0, (gk + 2) & 15);
    __builtin_amdgcn_s_barrier();
    asm volatile("s_waitcnt lgkmcnt(0)" ::: "memory");
    __builtin_amdgcn_sched_barrier(0);
    __builtin_amdgcn_s_setprio(1);
#pragma unroll
    for (int mi = 0; mi < 4; ++mi)
#pragma unroll
      for (int ni = 0; ni < 2; ++ni) {
        acc[mi + 4][ni] = __builtin_amdgcn_mfma_f32_16x16x32_bf16(aR[mi][0], b0[ni][0], acc[mi + 4][ni], 0, 0, 0);
        acc[mi + 4][ni] = __builtin_amdgcn_mfma_f32_16x16x32_bf16(aR[mi][1], b0[ni][1], acc[mi + 4][ni], 0, 0, 0);
      }
    __builtin_amdgcn_s_setprio(0);
    __builtin_amdgcn_s_barrier();
    // ---- phase 3: quad (mi4-7 x ni2-3); issue B1-half of gk+2; boundary ----
    if (gk + 2 < NG) stageB(Wsel((gk + 2) >> 4), c, 1, (gk + 2) & 15);
    __builtin_amdgcn_s_barrier();
    __builtin_amdgcn_s_setprio(1);
#pragma unroll
    for (int mi = 0; mi < 4; ++mi)
#pragma unroll
      for (int ni = 0; ni < 2; ++ni) {
        acc[mi + 4][ni + 2] = __builtin_amdgcn_mfma_f32_16x16x32_bf16(aR[mi][0], b1[ni][0], acc[mi + 4][ni + 2], 0, 0, 0);
        acc[mi + 4][ni + 2] = __builtin_amdgcn_mfma_f32_16x16x32_bf16(aR[mi][1], b1[ni][1], acc[mi + 4][ni + 2], 0, 0, 0);
      }
    __builtin_amdgcn_s_setprio(0);
    // boundary: drain B(gk+1)x4 + A(gk+1)x8 (12 oldest); keep B(gk+2)x4 flying.
    if (gk + 1 < NG) {
      if (gk + 2 < NG) { asm volatile("s_waitcnt vmcnt(4)" ::: "memory"); }
      else             { asm volatile("s_waitcnt vmcnt(0)" ::: "memory"); }
      writeA(c ^ 1); // cvt fp32->bf16, swizzled ds_write into next buffer
      asm volatile("s_waitcnt lgkmcnt(0)" ::: "memory"); // writes retired pre-barrier
    }
    __builtin_amdgcn_s_barrier();
    if (kt == 15) epilogue(gk >> 4); // C-write for this z; acc reset
  }
}

// ================= 256x256 8-phase GEMM (bf16 A via gld_lds) ===============
__device__ __forceinline__ void gemm256_core(
    const ushort_t* __restrict__ A, const ushort_t* __restrict__ Bw,
    float* __restrict__ Yf, const float* __restrict__ bias, int m0, int n0) {
  __shared__ __align__(16) ushort_t As[2][2][8192];
  __shared__ __align__(16) ushort_t Bs[2][2][8192];
  const int t = threadIdx.x;
  const int w = t >> 6, lane = t & 63, q4 = lane >> 4, l16 = lane & 15;
  const int wr = w >> 2, wc = w & 3;
  const int srow = t >> 3;
  const int scol = (((t & 7) ^ (srow & 7)) * 8);
  const int swz = l16 & 7;

  const ushort_t* gA = A + (size_t)(m0 + srow) * 1024 + scol;
  const ushort_t* gB = Bw + (size_t)(n0 + srow) * 1024 + scol;

  f32x4 acc[8][4];
  const f32x4 zero = {0.f, 0.f, 0.f, 0.f};
#pragma unroll
  for (int i = 0; i < 8; ++i)
#pragma unroll
    for (int j = 0; j < 4; ++j) acc[i][j] = zero;

  auto rdA = [&](int c, int mi, int kk) -> bf16x8 {
    const int rowh = mi * 16 + l16;
    const int slot = (kk * 4 + q4) ^ swz;
    return ldfrag(&As[c][wr][rowh * 64 + slot * 8]);
  };
  auto rdB = [&](int c, int ni, int kk) -> bf16x8 {
    const int rowh = (wc & 1) * 64 + ni * 16 + l16;
    const int slot = (kk * 4 + q4) ^ swz;
    return ldfrag(&Bs[c][wc >> 1][rowh * 64 + slot * 8]);
  };
  auto stageA = [&](int c, int h, int kt) {
    const ushort_t* g = gA + (size_t)(h * 128) * 1024 + kt * 64;
    gld_lds16(g, &As[c][h][t * 8]);
    gld_lds16(g + 64 * 1024, &As[c][h][4096 + t * 8]);
  };
  auto stageB = [&](int c, int h, int kt) {
    const ushort_t* g = gB + (size_t)(h * 128) * 1024 + kt * 64;
    gld_lds16(g, &Bs[c][h][t * 8]);
    gld_lds16(g + 64 * 1024, &Bs[c][h][4096 + t * 8]);
  };

  stageB(0, 0, 0); stageB(0, 1, 0);
  stageA(0, 0, 0); stageA(0, 1, 0);
  stageB(1, 0, 1); stageB(1, 1, 1);
  asm volatile("s_waitcnt vmcnt(4)" ::: "memory");
  __builtin_amdgcn_s_barrier();

  bf16x8 aR[4][2], b0[2][2], b1[2][2];
#pragma unroll 2
  for (int kt = 0; kt < NKT; ++kt) {
    const int c = kt & 1;
#pragma unroll
    for (int mi = 0; mi < 4; ++mi) { aR[mi][0] = rdA(c, mi, 0); aR[mi][1] = rdA(c, mi, 1); }
#pragma unroll
    for (int ni = 0; ni < 2; ++ni) { b0[ni][0] = rdB(c, ni, 0); b0[ni][1] = rdB(c, ni, 1); }
    if (kt + 1 < NKT) stageA(c ^ 1, 0, kt + 1);
    __builtin_amdgcn_s_barrier();
    asm volatile("s_waitcnt lgkmcnt(0)" ::: "memory");
    __builtin_amdgcn_sched_barrier(0);
    __builtin_amdgcn_s_setprio(1);
#pragma unroll
    for (int mi = 0; mi < 4; ++mi)
#pragma unroll
      for (int ni = 0; ni < 2; ++ni) {
        acc[mi][ni] = __builtin_amdgcn_mfma_f32_16x16x32_bf16(aR[mi][0], b0[ni][0], acc[mi][ni], 0, 0, 0);
        acc[mi][ni] = __builtin_amdgcn_mfma_f32_16x16x32_bf16(aR[mi][1], b0[ni][1], acc[mi][ni], 0, 0, 0);
      }
    __builtin_amdgcn_s_setprio(0);
    __builtin_amdgcn_s_barrier();
#pragma unroll
    for (int ni = 0; ni < 2; ++ni) { b1[ni][0] = rdB(c, ni + 2, 0); b1[ni][1] = rdB(c, ni + 2, 1); }
    if (kt + 1 < NKT) stageA(c ^ 1, 1, kt + 1);
    __builtin_amdgcn_s_barrier();
    asm volatile("s_waitcnt lgkmcnt(0)" ::: "memory");
    __builtin_amdgcn_sched_barrier(0);
    __builtin_amdgcn_s_setprio(1);
#pragma unroll
    for (int mi = 0; mi < 4; ++mi)
#pragma unroll
      for (int ni = 0; ni < 2; ++ni) {
        acc[mi][ni + 2] = __builtin_amdgcn_mfma_f32_16x16x32_bf16(aR[mi][0], b1[ni][0], acc[mi][ni + 2], 0, 0, 0);
        acc[mi][ni + 2] = __builtin_amdgcn_mfma_f32_16x16x32_bf16(aR[mi][1], b1[ni][1], acc[mi][ni + 2], 0, 0, 0);
      }
    __builtin_amdgcn_s_setprio(0);
    __builtin_amdgcn_s_barrier();
#pragma unroll
    for (int mi = 0; mi < 4; ++mi) { aR[mi][0] = rdA(c, mi + 4, 0); aR[mi][1] = rdA(c, mi + 4, 1); }
    if (kt + 2 < NKT) stageB(c, 0, kt + 2);
    __builtin_amdgcn_s_barrier();
    asm volatile("s_waitcnt lgkmcnt(0)" ::: "memory");
    __builtin_amdgcn_sched_barrier(0);
    __builtin_amdgcn_s_setprio(1);
#pragma unroll
    for (int mi = 0; mi < 4; ++mi)
#pragma unroll
      for (int ni = 0; ni < 2; ++ni) {
        acc[mi + 4][ni] = __builtin_amdgcn_mfma_f32_16x16x32_bf16(aR[mi][0], b0[ni][0], acc[mi + 4][ni], 0, 0, 0);
        acc[mi + 4][ni] = __builtin_amdgcn_mfma_f32_16x16x32_bf16(aR[mi][1], b0[ni][1], acc[mi + 4][ni], 0, 0, 0);
      }
    __builtin_amdgcn_s_setprio(0);
    __builtin_amdgcn_s_barrier();
    if (kt + 2 < NKT) stageB(c, 1, kt + 2);
    __builtin_amdgcn_s_barrier();
    __builtin_amdgcn_s_setprio(1);
#pragma unroll
    for (int mi = 0; mi < 4; ++mi)
#pragma unroll
      for (int ni = 0; ni < 2; ++ni) {
        acc[mi + 4][ni + 2] = __builtin_amdgcn_mfma_f32_16x16x32_bf16(aR[mi][0], b1[ni][0], acc[mi + 4][ni + 2], 0, 0, 0);
        acc[mi + 4][ni + 2] = __builtin_amdgcn_mfma_f32_16x16x32_bf16(aR[mi][1], b1[ni][1], acc[mi + 4][ni + 2], 0, 0, 0);
      }
    __builtin_amdgcn_s_setprio(0);
    if (kt < NKT - 2) {
      asm volatile("s_waitcnt vmcnt(4)" ::: "memory");
    } else if (kt == NKT - 2) {
      asm volatile("s_waitcnt vmcnt(0)" ::: "memory");
    }
    __builtin_amdgcn_s_barrier();
  }

#pragma unroll
  for (int mi = 0; mi < 8; ++mi)
#pragma unroll
    for (int ni = 0; ni < 4; ++ni) {
      const int col = n0 + wc * 64 + ni * 16 + l16;
      const float bv = bias[col];
#pragma unroll
      for (int r = 0; r < 4; ++r) {
        const int row = m0 + wr * 128 + mi * 16 + q4 * 4 + r;
        Yf[(size_t)row * 1024 + col] = acc[mi][ni][r] + bv;
      }
    }
}

__global__ __launch_bounds__(512, 2) void out256_kernel(
    const ushort_t* __restrict__ A, const ushort_t* __restrict__ Bw,
    float* __restrict__ Of, const float* __restrict__ bias) {
  const int raw = blockIdx.x;                       // 256 = 8 XCD * 32
  const int logical = (raw & 7) * 32 + (raw >> 3);
  const int m0 = (logical >> 2) * 256, n0 = (logical & 3) * 256;
  gemm256_core(A, Bw, Of, bias, m0, n0);
}

// ---------------- KV kernel: KVt[bh][e][d] = sum_s V[s,e]*K[s,d]; Ksum[bh][d]
__global__ __launch_bounds__(256) void kv_kernel(
    const ushort_t* __restrict__ Kp, const ushort_t* __restrict__ Vp,
    float* __restrict__ KVt, float* __restrict__ Ksum) {
  const int bh = blockIdx.y, b = bh >> 4, h = bh & 15;
  const int schunk = blockIdx.x * 256;
  const int t = threadIdx.x, w = t >> 6, lane = t & 63, q4 = lane >> 4, l16 = lane & 15;
  __shared__ ushort_t Ksh[64 * 66];
  __shared__ ushort_t Vsh[64 * 66];
  __shared__ float red[4][64];

  f32x4 acc[4];
  const f32x4 zero = {0.f, 0.f, 0.f, 0.f};
#pragma unroll
  for (int i = 0; i < 4; i++) acc[i] = zero;
  float ksum = 0.f;

  const int mat = t >> 7, tl = t & 127;
  const ushort_t* src = mat ? Vp : Kp;
  ushort_t* dsh = mat ? Vsh : Ksh;

  for (int tile = 0; tile < 4; tile++) {
    const int s0 = schunk + tile * 64;
#pragma unroll
    for (int i = 0; i < 4; i++) {
      int idx = i * 1024 + tl * 8;
      int r = idx >> 6, c = idx & 63;
      const ushort_t* g = src + (size_t)(b * 4096 + s0 + r) * 1024 + h * 64 + c;
      uint4 u = *(const uint4*)g;
      unsigned int* p = (unsigned int*)&dsh[r * 66 + c];
      p[0] = u.x; p[1] = u.y; p[2] = u.z; p[3] = u.w;
    }
    __syncthreads();
#pragma unroll
    for (int ks = 0; ks < 2; ks++) {
      ushort_t tb[8];
#pragma unroll
      for (int j = 0; j < 8; j++) tb[j] = Ksh[(ks * 32 + q4 * 8 + j) * 66 + w * 16 + l16];
      bf16x8 bfr; __builtin_memcpy(&bfr, tb, 16);
#pragma unroll
      for (int mi = 0; mi < 4; mi++) {
        ushort_t ta[8];
#pragma unroll
        for (int j = 0; j < 8; j++) ta[j] = Vsh[(ks * 32 + q4 * 8 + j) * 66 + mi * 16 + l16];
        bf16x8 afr; __builtin_memcpy(&afr, ta, 16);
        acc[mi] = __builtin_amdgcn_mfma_f32_16x16x32_bf16(afr, bfr, acc[mi], 0, 0, 0);
      }
    }
    {
      int d = t & 63;
#pragma unroll
      for (int r = 0; r < 16; r++) ksum += b2f(Ksh[((t >> 6) * 16 + r) * 66 + d]);
    }
    __syncthreads();
  }
#pragma unroll
  for (int mi = 0; mi < 4; mi++)
#pragma unroll
    for (int r = 0; r < 4; r++) {
      int e = mi * 16 + q4 * 4 + r, d = w * 16 + l16;
      atomicAdd(&KVt[(size_t)bh * 4096 + e * 64 + d], acc[mi][r]);
    }
  red[t >> 6][t & 63] = ksum;
  __syncthreads();
  if (t < 64) atomicAdd(&Ksum[bh * 64 + t], red[0][t] + red[1][t] + red[2][t] + red[3][t]);
}

// ---------------- num kernel ----------------
__global__ __launch_bounds__(256) void num_kernel(
    const ushort_t* __restrict__ Qp, const float* __restrict__ KVt,
    const float* __restrict__ Ksum, ushort_t* __restrict__ Oc) {
  const int bh = blockIdx.y, b = bh >> 4, h = bh & 15;
  const int sblk = blockIdx.x * 256;
  const int t = threadIdx.x, w = t >> 6, lane = t & 63, q4 = lane >> 4, l16 = lane & 15;
  __shared__ __align__(16) ushort_t KVsh[64 * 72];
  __shared__ float Ks_sh[64];
  __shared__ float rden[256];

#pragma unroll
  for (int i = 0; i < 16; i++) {
    int idx = i * 256 + t;
    int e = idx >> 6, d = idx & 63;
    KVsh[e * 72 + d] = f2bf(KVt[(size_t)bh * 4096 + idx]);
  }
  if (t < 64) Ks_sh[t] = Ksum[bh * 64 + t];
  __syncthreads();

  {
    const ushort_t* qrow = Qp + (size_t)(b * 4096 + sblk + t) * 1024 + h * 64;
    float den = 1e-6f;
#pragma unroll
    for (int j = 0; j < 8; j++) {
      bf16x8 qv = ldfrag(qrow + j * 8);
#pragma unroll
      for (int e = 0; e < 8; e++) den += (float)qv[e] * Ks_sh[j * 8 + e];
    }
    rden[t] = 1.f / den;
  }
  __syncthreads();

  f32x4 acc[4][4];
  const f32x4 zero = {0.f, 0.f, 0.f, 0.f};
#pragma unroll
  for (int i = 0; i < 4; i++)
#pragma unroll
    for (int j = 0; j < 4; j++) acc[i][j] = zero;

#pragma unroll
  for (int ks = 0; ks < 2; ks++) {
    bf16x8 af[4], bfr[4];
#pragma unroll
    for (int mi = 0; mi < 4; mi++)
      af[mi] = ldfrag(Qp + (size_t)(b * 4096 + sblk + w * 64 + mi * 16 + l16) * 1024 + h * 64 + ks * 32 + q4 * 8);
#pragma unroll
    for (int ni = 0; ni < 4; ni++)
      bfr[ni] = ldfrag(&KVsh[(ni * 16 + l16) * 72 + ks * 32 + q4 * 8]);
#pragma unroll
    for (int mi = 0; mi < 4; mi++)
#pragma unroll
      for (int ni = 0; ni < 4; ni++)
        acc[mi][ni] = __builtin_amdgcn_mfma_f32_16x16x32_bf16(af[mi], bfr[ni], acc[mi][ni], 0, 0, 0);
  }
#pragma unroll
  for (int mi = 0; mi < 4; mi++)
#pragma unroll
    for (int ni = 0; ni < 4; ni++) {
      int e = ni * 16 + l16;
#pragma unroll
      for (int r = 0; r < 4; r++) {
        int srow = w * 64 + mi * 16 + q4 * 4 + r;
        float vv = acc[mi][ni][r] * rden[srow];
        Oc[(size_t)(b * 4096 + sblk + srow) * 1024 + h * 64 + e] = f2bf(vv);
      }
    }
}

extern "C" void kernel_launch(void* const* d_in, const int* in_sizes, int n_in,
                              void* d_out, int out_size, void* d_ws, size_t ws_size,
                              hipStream_t stream) {
  const float* q  = (const float*)d_in[0];
  const float* k  = (const float*)d_in[1];
  const float* v  = (const float*)d_in[2];
  const float* Wq = (const float*)d_in[3];
  const float* Wk = (const float*)d_in[4];
  const float* Wv = (const float*)d_in[5];
  const float* Wo = (const float*)d_in[6];
  const float* bo = (const float*)d_in[7];

  char* ws = (char*)d_ws;
  ushort_t* wqb = (ushort_t*)ws;
  ushort_t* wkb = wqb + (size_t)1024 * 1024;
  ushort_t* wvb = wkb + (size_t)1024 * 1024;
  ushort_t* wob = wvb + (size_t)1024 * 1024;
  ushort_t* Qp  = (ushort_t*)(ws + 4 * (size_t)2097152);
  ushort_t* Kp  = Qp + (size_t)MM * DD;
  ushort_t* Vp  = Kp + (size_t)MM * DD;
  float* KVt    = (float*)((char*)(Vp + (size_t)MM * DD));
  float* KsumP  = KVt + (size_t)64 * 4096;
  ushort_t* Oc  = (ushort_t*)(KsumP + (size_t)64 * 64);
  float* outp   = (float*)d_out;

  prep_kernel<<<dim3(1024, 5), 256, 0, stream>>>(Wq, Wk, Wv, Wo, wqb, wkb, wvb, wob, KVt);
  projf_kernel<<<dim3(256), 512, 0, stream>>>(q, k, v, wqb, wkb, wvb, Qp, Kp, Vp);
  kv_kernel<<<dim3(16, 64), 256, 0, stream>>>(Kp, Vp, KVt, KsumP);
  num_kernel<<<dim3(16, 64), 256, 0, stream>>>(Qp, KVt, KsumP, Oc);
  out256_kernel<<<dim3(256), 512, 0, stream>>>(Oc, wob, outp, bo);
}

// Round 4
// 429.274 us; speedup vs baseline: 1.1109x; 1.1109x over previous
//
#include <hip/hip_runtime.h>

// LinearAttention: B=4, S=4096, D=1024, H=16, DK=64
// R7: REVERT to R4 (best verified: 430us) after R5/R6's fused fp32-A
//     reg-staging regressed proj 130->237us (m151: reg-staging costs
//     16-35% vs global_load_lds; plus 2x A bytes + serial cvt/ds_write
//     at every K-tile boundary). Only delta vs R4: memset+cast4 fused
//     into one prep kernel (7 -> 6 dispatches).
// R4 state: 8-phase 256^2 proj = 793 TF (MfmaUtil 34%, bank-conflict 0),
//     within ~7% of the m248 structural ceiling (848 TF) at K=1024.

typedef unsigned short ushort_t;
typedef __bf16 bf16x8 __attribute__((ext_vector_type(8)));
typedef float f32x4 __attribute__((ext_vector_type(4)));
typedef void gvoid_t __attribute__((address_space(1)));
typedef void svoid_t __attribute__((address_space(3)));

#define BB 4
#define SS 4096
#define DD 1024
#define HH 16
#define DKk 64
#define MM (BB * SS) /* 16384 */
#define NKT 16       /* K=1024 in 16 tiles of 64 */

__device__ __forceinline__ ushort_t f2bf(float f) {
  unsigned int u = __float_as_uint(f);
  u += 0x7fffu + ((u >> 16) & 1u); // RNE
  return (ushort_t)(u >> 16);
}
__device__ __forceinline__ float b2f(ushort_t h) {
  return __uint_as_float(((unsigned int)h) << 16);
}
__device__ __forceinline__ void gld_lds16(const ushort_t* g, ushort_t* l) {
  // async global->LDS, 16B per lane; LDS dest = wave-uniform base + lane*16
  __builtin_amdgcn_global_load_lds((gvoid_t*)g, (svoid_t*)l, 16, 0, 0);
}
__device__ __forceinline__ bf16x8 ldfrag(const ushort_t* p) {
  return *(const bf16x8*)p; // 16B aligned at all call sites
}

// ---------------- cast kernel (q,k,v fp32 -> bf16) ----------------
__global__ __launch_bounds__(256) void cast3_kernel(
    const float* __restrict__ q, const float* __restrict__ k, const float* __restrict__ v,
    ushort_t* __restrict__ qd, ushort_t* __restrict__ kd, ushort_t* __restrict__ vd) {
  const int z = blockIdx.y;
  const float* s = (z == 0) ? q : (z == 1) ? k : v;
  ushort_t* d = (z == 0) ? qd : (z == 1) ? kd : vd;
  size_t i = ((size_t)blockIdx.x * 256 + threadIdx.x) * 4;
  float4 f = *(const float4*)(s + i);
  ushort4 o;
  o.x = f2bf(f.x); o.y = f2bf(f.y); o.z = f2bf(f.z); o.w = f2bf(f.w);
  *(ushort4*)(d + i) = o;
}

// ------------- prep: cast 4 weight mats fp32->bf16 + zero KVt/Ksum --------
__global__ __launch_bounds__(256) void prep_kernel(
    const float* __restrict__ a, const float* __restrict__ b,
    const float* __restrict__ c, const float* __restrict__ e,
    ushort_t* __restrict__ ad, ushort_t* __restrict__ bd,
    ushort_t* __restrict__ cd, ushort_t* __restrict__ ed,
    float* __restrict__ zbuf) {
  const int z = blockIdx.y;
  if (z == 4) { // zero KVt (64*4096) + Ksum (64*64) = 266240 floats
    const size_t tot = (size_t)64 * 4096 + 64 * 64;
    for (size_t j = (size_t)blockIdx.x * 256 + threadIdx.x; j < tot; j += (size_t)1024 * 256)
      zbuf[j] = 0.f;
    return;
  }
  const float* s = (z == 0) ? a : (z == 1) ? b : (z == 2) ? c : e;
  ushort_t* d = (z == 0) ? ad : (z == 1) ? bd : (z == 2) ? cd : ed;
  size_t i = ((size_t)blockIdx.x * 256 + threadIdx.x) * 4;
  float4 f = *(const float4*)(s + i);
  ushort4 o;
  o.x = f2bf(f.x); o.y = f2bf(f.y); o.z = f2bf(f.z); o.w = f2bf(f.w);
  *(ushort4*)(d + i) = o;
}

// ================= 256x256 8-phase GEMM core =================
// Y[M,N] = act(A[M,K] * Bw[N,K]^T). BM=BN=256, BK=64, 512 thr = 8 waves (2x4).
// LDS 128 KiB: [buf][half(128rows)][128*64] for A and B, double-buffered.
// Staging: gld_lds 16B/lane, LINEAR LDS dest; global source granule
// pre-swizzled s^=(row&7) so ds_read with same XOR is conflict-free (rule 21).
__device__ __forceinline__ void gemm256_core(
    const ushort_t* __restrict__ A, const ushort_t* __restrict__ Bw,
    ushort_t* __restrict__ Ybf, float* __restrict__ Yf,
    const float* __restrict__ bias, bool act, int m0, int n0) {
  __shared__ __align__(16) ushort_t As[2][2][8192];
  __shared__ __align__(16) ushort_t Bs[2][2][8192];
  const int t = threadIdx.x;
  const int w = t >> 6, lane = t & 63, q4 = lane >> 4, l16 = lane & 15;
  const int wr = w >> 2, wc = w & 3; // 2(M) x 4(N) wave grid; wave tile 128x64
  const int srow = t >> 3;                          // staging row (0..63 per instr)
  const int scol = (((t & 7) ^ (srow & 7)) * 8);    // pre-swizzled global granule
  const int swz = l16 & 7;                          // read-side XOR (rowh&7)

  const ushort_t* gA = A + (size_t)(m0 + srow) * 1024 + scol;
  const ushort_t* gB = Bw + (size_t)(n0 + srow) * 1024 + scol;

  f32x4 acc[8][4];
  const f32x4 zero = {0.f, 0.f, 0.f, 0.f};
#pragma unroll
  for (int i = 0; i < 8; ++i)
#pragma unroll
    for (int j = 0; j < 4; ++j) acc[i][j] = zero;

  auto rdA = [&](int c, int mi, int kk) -> bf16x8 {
    const int rowh = mi * 16 + l16;                 // row within wave's A-half
    const int slot = (kk * 4 + q4) ^ swz;
    return ldfrag(&As[c][wr][rowh * 64 + slot * 8]);
  };
  auto rdB = [&](int c, int ni, int kk) -> bf16x8 {
    const int rowh = (wc & 1) * 64 + ni * 16 + l16; // row within B-half (wc>>1)
    const int slot = (kk * 4 + q4) ^ swz;
    return ldfrag(&Bs[c][wc >> 1][rowh * 64 + slot * 8]);
  };
  auto stageA = [&](int c, int h, int kt) { // one 128x64 half-tile = 2 loads
    const ushort_t* g = gA + (size_t)(h * 128) * 1024 + kt * 64;
    gld_lds16(g, &As[c][h][t * 8]);
    gld_lds16(g + 64 * 1024, &As[c][h][4096 + t * 8]);
  };
  auto stageB = [&](int c, int h, int kt) {
    const ushort_t* g = gB + (size_t)(h * 128) * 1024 + kt * 64;
    gld_lds16(g, &Bs[c][h][t * 8]);
    gld_lds16(g + 64 * 1024, &Bs[c][h][4096 + t * 8]);
  };

  // prologue: issue halves {B0,B1,A0,A1}@kt0 -> buf0, {B0,B1}@kt1 -> buf1.
  // vmcnt(4): kt0's 4 halves (8 oldest loads) landed; 2 newest may fly.
  stageB(0, 0, 0); stageB(0, 1, 0);
  stageA(0, 0, 0); stageA(0, 1, 0);
  stageB(1, 0, 1); stageB(1, 1, 1);
  asm volatile("s_waitcnt vmcnt(4)" ::: "memory");
  __builtin_amdgcn_s_barrier();

  bf16x8 aR[4][2], b0[2][2], b1[2][2];
#pragma unroll 2
  for (int kt = 0; kt < NKT; ++kt) {
    const int c = kt & 1;
    // ---- phase 0: quad (mi0-3 x ni0-1); issue A0-half of kt+1 ----
#pragma unroll
    for (int mi = 0; mi < 4; ++mi) { aR[mi][0] = rdA(c, mi, 0); aR[mi][1] = rdA(c, mi, 1); }
#pragma unroll
    for (int ni = 0; ni < 2; ++ni) { b0[ni][0] = rdB(c, ni, 0); b0[ni][1] = rdB(c, ni, 1); }
    if (kt + 1 < NKT) stageA(c ^ 1, 0, kt + 1); // overwrites kt-1's A0 (reads done ph2 of kt-1)
    __builtin_amdgcn_s_barrier();
    asm volatile("s_waitcnt lgkmcnt(0)" ::: "memory");
    __builtin_amdgcn_sched_barrier(0);
    __builtin_amdgcn_s_setprio(1);
#pragma unroll
    for (int mi = 0; mi < 4; ++mi)
#pragma unroll
      for (int ni = 0; ni < 2; ++ni) {
        acc[mi][ni] = __builtin_amdgcn_mfma_f32_16x16x32_bf16(aR[mi][0], b0[ni][0], acc[mi][ni], 0, 0, 0);
        acc[mi][ni] = __builtin_amdgcn_mfma_f32_16x16x32_bf16(aR[mi][1], b0[ni][1], acc[mi][ni], 0, 0, 0);
      }
    __builtin_amdgcn_s_setprio(0);
    __builtin_amdgcn_s_barrier();
    // ---- phase 1: quad (mi0-3 x ni2-3); issue A1-half of kt+1 ----
#pragma unroll
    for (int ni = 0; ni < 2; ++ni) { b1[ni][0] = rdB(c, ni + 2, 0); b1[ni][1] = rdB(c, ni + 2, 1); }
    if (kt + 1 < NKT) stageA(c ^ 1, 1, kt + 1);
    __builtin_amdgcn_s_barrier();
    asm volatile("s_waitcnt lgkmcnt(0)" ::: "memory");
    __builtin_amdgcn_sched_barrier(0);
    __builtin_amdgcn_s_setprio(1);
#pragma unroll
    for (int mi = 0; mi < 4; ++mi)
#pragma unroll
      for (int ni = 0; ni < 2; ++ni) {
        acc[mi][ni + 2] = __builtin_amdgcn_mfma_f32_16x16x32_bf16(aR[mi][0], b1[ni][0], acc[mi][ni + 2], 0, 0, 0);
        acc[mi][ni + 2] = __builtin_amdgcn_mfma_f32_16x16x32_bf16(aR[mi][1], b1[ni][1], acc[mi][ni + 2], 0, 0, 0);
      }
    __builtin_amdgcn_s_setprio(0);
    __builtin_amdgcn_s_barrier();
    // ---- phase 2: quad (mi4-7 x ni0-1); issue B0-half of kt+2 ----
#pragma unroll
    for (int mi = 0; mi < 4; ++mi) { aR[mi][0] = rdA(c, mi + 4, 0); aR[mi][1] = rdA(c, mi + 4, 1); }
    if (kt + 2 < NKT) stageB(c, 0, kt + 2); // overwrites kt's B0 (B reads done phase 1)
    __builtin_amdgcn_s_barrier();
    asm volatile("s_waitcnt lgkmcnt(0)" ::: "memory");
    __builtin_amdgcn_sched_barrier(0);
    __builtin_amdgcn_s_setprio(1);
#pragma unroll
    for (int mi = 0; mi < 4; ++mi)
#pragma unroll
      for (int ni = 0; ni < 2; ++ni) {
        acc[mi + 4][ni] = __builtin_amdgcn_mfma_f32_16x16x32_bf16(aR[mi][0], b0[ni][0], acc[mi + 4][ni], 0, 0, 0);
        acc[mi + 4][ni] = __builtin_amdgcn_mfma_f32_16x16x32_bf16(aR[mi][1], b0[ni][1], acc[mi + 4][ni], 0, 0, 0);
      }
    __builtin_amdgcn_s_setprio(0);
    __builtin_amdgcn_s_barrier();
    // ---- phase 3: quad (mi4-7 x ni2-3); issue B1-half of kt+2; boundary vmcnt ----
    if (kt + 2 < NKT) stageB(c, 1, kt + 2);
    __builtin_amdgcn_s_barrier();
    __builtin_amdgcn_s_setprio(1);
#pragma unroll
    for (int mi = 0; mi < 4; ++mi)
#pragma unroll
      for (int ni = 0; ni < 2; ++ni) {
        acc[mi + 4][ni + 2] = __builtin_amdgcn_mfma_f32_16x16x32_bf16(aR[mi][0], b1[ni][0], acc[mi + 4][ni + 2], 0, 0, 0);
        acc[mi + 4][ni + 2] = __builtin_amdgcn_mfma_f32_16x16x32_bf16(aR[mi][1], b1[ni][1], acc[mi + 4][ni + 2], 0, 0, 0);
      }
    __builtin_amdgcn_s_setprio(0);
    // counted drain: kt+1's 4 halves landed; only B{0,1}@kt+2 (4 loads) in flight
    if (kt < NKT - 2) {
      asm volatile("s_waitcnt vmcnt(4)" ::: "memory");
    } else if (kt == NKT - 2) {
      asm volatile("s_waitcnt vmcnt(0)" ::: "memory"); // last halves: full drain
    }
    __builtin_amdgcn_s_barrier();
  }

  // epilogue: C layout col=l16, row=q4*4+r within each 16x16 fragment
  if (Yf) {
#pragma unroll
    for (int mi = 0; mi < 8; ++mi)
#pragma unroll
      for (int ni = 0; ni < 4; ++ni) {
        const int col = n0 + wc * 64 + ni * 16 + l16;
        const float bv = bias[col];
#pragma unroll
        for (int r = 0; r < 4; ++r) {
          const int row = m0 + wr * 128 + mi * 16 + q4 * 4 + r;
          Yf[(size_t)row * 1024 + col] = acc[mi][ni][r] + bv;
        }
      }
  } else {
#pragma unroll
    for (int mi = 0; mi < 8; ++mi)
#pragma unroll
      for (int ni = 0; ni < 4; ++ni) {
        const int col = n0 + wc * 64 + ni * 16 + l16;
#pragma unroll
        for (int r = 0; r < 4; ++r) {
          const int row = m0 + wr * 128 + mi * 16 + q4 * 4 + r;
          float vv = acc[mi][ni][r];
          if (act) vv = (vv > 0.f) ? (vv + 1.f) : __expf(vv); // elu(x)+1
          Ybf[(size_t)row * 1024 + col] = f2bf(vv);
        }
      }
  }
}

// proj: 3 GEMMs of [16384,1024]x[1024,1024]^T, 64x4=256 tiles each, 768 blocks.
__global__ __launch_bounds__(512, 2) void proj256_kernel(
    const ushort_t* __restrict__ qa, const ushort_t* __restrict__ ka, const ushort_t* __restrict__ va,
    const ushort_t* __restrict__ wq, const ushort_t* __restrict__ wk, const ushort_t* __restrict__ wv,
    ushort_t* __restrict__ Qp, ushort_t* __restrict__ Kp, ushort_t* __restrict__ Vp) {
  const int raw = blockIdx.x;                       // 768 = 8 XCD * 96
  const int logical = (raw & 7) * 96 + (raw >> 3);  // bijective chunked XCD swizzle
  const int z = logical >> 8;
  const int rem = logical & 255;
  const int m0 = (rem >> 2) * 256, n0 = (rem & 3) * 256;
  const ushort_t* A = (z == 0) ? qa : (z == 1) ? ka : va;
  const ushort_t* Bw = (z == 0) ? wq : (z == 1) ? wk : wv;
  ushort_t* Y = (z == 0) ? Qp : (z == 1) ? Kp : Vp;
  gemm256_core(A, Bw, Y, nullptr, nullptr, z < 2, m0, n0);
}

__global__ __launch_bounds__(512, 2) void out256_kernel(
    const ushort_t* __restrict__ A, const ushort_t* __restrict__ Bw,
    float* __restrict__ Of, const float* __restrict__ bias) {
  const int raw = blockIdx.x;                       // 256 = 8 XCD * 32
  const int logical = (raw & 7) * 32 + (raw >> 3);
  const int m0 = (logical >> 2) * 256, n0 = (logical & 3) * 256;
  gemm256_core(A, Bw, nullptr, Of, bias, false, m0, n0);
}

// ---------------- KV kernel: KVt[bh][e][d] = sum_s V[s,e]*K[s,d]; Ksum[bh][d]
__global__ __launch_bounds__(256) void kv_kernel(
    const ushort_t* __restrict__ Kp, const ushort_t* __restrict__ Vp,
    float* __restrict__ KVt, float* __restrict__ Ksum) {
  const int bh = blockIdx.y, b = bh >> 4, h = bh & 15;
  const int schunk = blockIdx.x * 256;
  const int t = threadIdx.x, w = t >> 6, lane = t & 63, q4 = lane >> 4, l16 = lane & 15;
  __shared__ ushort_t Ksh[64 * 66];
  __shared__ ushort_t Vsh[64 * 66];
  __shared__ float red[4][64];

  f32x4 acc[4];
  const f32x4 zero = {0.f, 0.f, 0.f, 0.f};
#pragma unroll
  for (int i = 0; i < 4; i++) acc[i] = zero;
  float ksum = 0.f;

  const int mat = t >> 7, tl = t & 127;
  const ushort_t* src = mat ? Vp : Kp;
  ushort_t* dsh = mat ? Vsh : Ksh;

  for (int tile = 0; tile < 4; tile++) {
    const int s0 = schunk + tile * 64;
#pragma unroll
    for (int i = 0; i < 4; i++) {
      int idx = i * 1024 + tl * 8;
      int r = idx >> 6, c = idx & 63;
      const ushort_t* g = src + (size_t)(b * 4096 + s0 + r) * 1024 + h * 64 + c;
      uint4 u = *(const uint4*)g;
      unsigned int* p = (unsigned int*)&dsh[r * 66 + c];
      p[0] = u.x; p[1] = u.y; p[2] = u.z; p[3] = u.w;
    }
    __syncthreads();
#pragma unroll
    for (int ks = 0; ks < 2; ks++) {
      ushort_t tb[8];
#pragma unroll
      for (int j = 0; j < 8; j++) tb[j] = Ksh[(ks * 32 + q4 * 8 + j) * 66 + w * 16 + l16];
      bf16x8 bfr; __builtin_memcpy(&bfr, tb, 16);
#pragma unroll
      for (int mi = 0; mi < 4; mi++) {
        ushort_t ta[8];
#pragma unroll
        for (int j = 0; j < 8; j++) ta[j] = Vsh[(ks * 32 + q4 * 8 + j) * 66 + mi * 16 + l16];
        bf16x8 afr; __builtin_memcpy(&afr, ta, 16);
        acc[mi] = __builtin_amdgcn_mfma_f32_16x16x32_bf16(afr, bfr, acc[mi], 0, 0, 0);
      }
    }
    {
      int d = t & 63;
#pragma unroll
      for (int r = 0; r < 16; r++) ksum += b2f(Ksh[((t >> 6) * 16 + r) * 66 + d]);
    }
    __syncthreads();
  }
#pragma unroll
  for (int mi = 0; mi < 4; mi++)
#pragma unroll
    for (int r = 0; r < 4; r++) {
      int e = mi * 16 + q4 * 4 + r, d = w * 16 + l16;
      atomicAdd(&KVt[(size_t)bh * 4096 + e * 64 + d], acc[mi][r]);
    }
  red[t >> 6][t & 63] = ksum;
  __syncthreads();
  if (t < 64) atomicAdd(&Ksum[bh * 64 + t], red[0][t] + red[1][t] + red[2][t] + red[3][t]);
}

// ---------------- num kernel ----------------
__global__ __launch_bounds__(256) void num_kernel(
    const ushort_t* __restrict__ Qp, const float* __restrict__ KVt,
    const float* __restrict__ Ksum, ushort_t* __restrict__ Oc) {
  const int bh = blockIdx.y, b = bh >> 4, h = bh & 15;
  const int sblk = blockIdx.x * 256;
  const int t = threadIdx.x, w = t >> 6, lane = t & 63, q4 = lane >> 4, l16 = lane & 15;
  __shared__ __align__(16) ushort_t KVsh[64 * 72];
  __shared__ float Ks_sh[64];
  __shared__ float rden[256];

#pragma unroll
  for (int i = 0; i < 16; i++) {
    int idx = i * 256 + t;
    int e = idx >> 6, d = idx & 63;
    KVsh[e * 72 + d] = f2bf(KVt[(size_t)bh * 4096 + idx]);
  }
  if (t < 64) Ks_sh[t] = Ksum[bh * 64 + t];
  __syncthreads();

  {
    const ushort_t* qrow = Qp + (size_t)(b * 4096 + sblk + t) * 1024 + h * 64;
    float den = 1e-6f;
#pragma unroll
    for (int j = 0; j < 8; j++) {
      bf16x8 qv = ldfrag(qrow + j * 8);
#pragma unroll
      for (int e = 0; e < 8; e++) den += (float)qv[e] * Ks_sh[j * 8 + e];
    }
    rden[t] = 1.f / den;
  }
  __syncthreads();

  f32x4 acc[4][4];
  const f32x4 zero = {0.f, 0.f, 0.f, 0.f};
#pragma unroll
  for (int i = 0; i < 4; i++)
#pragma unroll
    for (int j = 0; j < 4; j++) acc[i][j] = zero;

#pragma unroll
  for (int ks = 0; ks < 2; ks++) {
    bf16x8 af[4], bfr[4];
#pragma unroll
    for (int mi = 0; mi < 4; mi++)
      af[mi] = ldfrag(Qp + (size_t)(b * 4096 + sblk + w * 64 + mi * 16 + l16) * 1024 + h * 64 + ks * 32 + q4 * 8);
#pragma unroll
    for (int ni = 0; ni < 4; ni++)
      bfr[ni] = ldfrag(&KVsh[(ni * 16 + l16) * 72 + ks * 32 + q4 * 8]);
#pragma unroll
    for (int mi = 0; mi < 4; mi++)
#pragma unroll
      for (int ni = 0; ni < 4; ni++)
        acc[mi][ni] = __builtin_amdgcn_mfma_f32_16x16x32_bf16(af[mi], bfr[ni], acc[mi][ni], 0, 0, 0);
  }
#pragma unroll
  for (int mi = 0; mi < 4; mi++)
#pragma unroll
    for (int ni = 0; ni < 4; ni++) {
      int e = ni * 16 + l16;
#pragma unroll
      for (int r = 0; r < 4; r++) {
        int srow = w * 64 + mi * 16 + q4 * 4 + r;
        float vv = acc[mi][ni][r] * rden[srow];
        Oc[(size_t)(b * 4096 + sblk + srow) * 1024 + h * 64 + e] = f2bf(vv);
      }
    }
}

extern "C" void kernel_launch(void* const* d_in, const int* in_sizes, int n_in,
                              void* d_out, int out_size, void* d_ws, size_t ws_size,
                              hipStream_t stream) {
  const float* q  = (const float*)d_in[0];
  const float* k  = (const float*)d_in[1];
  const float* v  = (const float*)d_in[2];
  const float* Wq = (const float*)d_in[3];
  const float* Wk = (const float*)d_in[4];
  const float* Wv = (const float*)d_in[5];
  const float* Wo = (const float*)d_in[6];
  const float* bo = (const float*)d_in[7];

  char* ws = (char*)d_ws;
  const size_t SZ_IN = (size_t)MM * DD * 2; // 33,554,432 B per bf16 [16384,1024]
  ushort_t* qbf = (ushort_t*)(ws);
  ushort_t* kbf = (ushort_t*)(ws + SZ_IN);
  ushort_t* vbf = (ushort_t*)(ws + 2 * SZ_IN);
  ushort_t* wqb = (ushort_t*)(ws + 3 * SZ_IN);
  ushort_t* wkb = wqb + (size_t)1024 * 1024;
  ushort_t* wvb = wkb + (size_t)1024 * 1024;
  ushort_t* wob = wvb + (size_t)1024 * 1024;
  ushort_t* Qp  = (ushort_t*)(ws + 3 * SZ_IN + 4 * (size_t)2097152);
  ushort_t* Kp  = Qp + (size_t)MM * DD;
  ushort_t* Vp  = Kp + (size_t)MM * DD;
  float* KVt    = (float*)((char*)(Vp + (size_t)MM * DD));
  float* KsumP  = KVt + (size_t)64 * 4096;
  ushort_t* Oc  = qbf; // reuse: qbf dead after proj dispatch
  float* outp   = (float*)d_out;

  prep_kernel<<<dim3(1024, 5), 256, 0, stream>>>(Wq, Wk, Wv, Wo, wqb, wkb, wvb, wob, KVt);
  cast3_kernel<<<dim3(16384, 3), 256, 0, stream>>>(q, k, v, qbf, kbf, vbf);
  proj256_kernel<<<dim3(768), 512, 0, stream>>>(qbf, kbf, vbf, wqb, wkb, wvb, Qp, Kp, Vp);
  kv_kernel<<<dim3(16, 64), 256, 0, stream>>>(Kp, Vp, KVt, KsumP);
  num_kernel<<<dim3(16, 64), 256, 0, stream>>>(Qp, KVt, KsumP, Oc);
  out256_kernel<<<dim3(256), 512, 0, stream>>>(Oc, wob, outp, bo);
}